// Round 4
// baseline (1514.870 us; speedup 1.0000x reference)
//
#include <hip/hip_runtime.h>
#include <hip/hip_bf16.h>

#define DM 200
#define DIE 400
#define LSEQ 256
#define NB 256

typedef __hip_bfloat16 bf16;
typedef const float* fp;
typedef __attribute__((ext_vector_type(8))) short short8;
typedef __attribute__((ext_vector_type(4))) short short4_t;
typedef __attribute__((ext_vector_type(4))) float f32x4;

__device__ __forceinline__ float b2f(bf16 x) { return __bfloat162float(x); }
__device__ __forceinline__ bf16  f2b(float x) { return __float2bfloat16(x); }

// f32 -> bf16 bits (round-to-nearest-even)
__device__ __forceinline__ unsigned short f2bbits(float f) {
    union { float f; unsigned int u; } c; c.f = f;
    unsigned int u = c.u;
    unsigned int r = (u + 0x7fffu + ((u >> 16) & 1u)) >> 16;
    return (unsigned short)r;
}
__device__ __forceinline__ void stf(float* p, float v) { *p = v; }
__device__ __forceinline__ void stf(bf16* p, float v) { *p = f2b(v); }

// ---------------- weight f32->bf16 pre-convert (6 arrays packed, both layers) ----------------
// float counts: in_proj 320000 | x_proj 36000 | out_proj 160000 | ffn1 320000 | ffn2 320000 | dtW 10400
#define W_XP_OFF 320000
#define W_OP_OFF 356000
#define W_F1_OFF 516000
#define W_F2_OFF 836000
#define W_DT_OFF 1156000
#define W_TOTAL  1166400
#define W_BYTES  2332800

__global__ __launch_bounds__(256) void wcvt_kernel(fp a0, fp a1, fp a2, fp a3, fp a4, fp a5,
                                                   bf16* __restrict__ dst) {
    int g = blockIdx.x * 256 + threadIdx.x;
    if (g >= W_TOTAL / 4) return;
    int idx = g * 4;
    const float* src;
    int off;
    if (idx < W_XP_OFF)      { src = a0; off = idx; }
    else if (idx < W_OP_OFF) { src = a1; off = idx - W_XP_OFF; }
    else if (idx < W_F1_OFF) { src = a2; off = idx - W_OP_OFF; }
    else if (idx < W_F2_OFF) { src = a3; off = idx - W_F1_OFF; }
    else if (idx < W_DT_OFF) { src = a4; off = idx - W_F2_OFF; }
    else                     { src = a5; off = idx - W_DT_OFF; }
    float4 v = *(const float4*)(src + off);
    short4_t o;
    o.x = (short)f2bbits(v.x); o.y = (short)f2bbits(v.y);
    o.z = (short)f2bbits(v.z); o.w = (short)f2bbits(v.w);
    *(short4_t*)((short*)dst + idx) = o;
}

// ---------------- generic f32 -> bf16 convert (for emb chunk) ----------------
__global__ __launch_bounds__(256) void cvt_kernel(const float* __restrict__ src,
                                                  bf16* __restrict__ dst, int n4) {
    int g = blockIdx.x * 256 + threadIdx.x;
    if (g >= n4) return;
    int idx = g * 4;
    float4 v = *(const float4*)(src + idx);
    short4_t o;
    o.x = (short)f2bbits(v.x); o.y = (short)f2bbits(v.y);
    o.z = (short)f2bbits(v.z); o.w = (short)f2bbits(v.w);
    *(short4_t*)((short*)dst + idx) = o;
}

// ---------------- MFMA NT GEMM: C[m,n] = sum_k A[m,k]*W[n,k] (+epilogue) ----------------
// A and W both bf16 in memory -> staging is pure short8 vector loads (no convert).
// Block tile 128(m) x 128(n), K-step 32, 4 waves in 2x2; wave subtile 64x64 = 4x4 MFMA tiles.
// EPI: 0=none, 2=gelu_exact(x+bias), 3=x+bias, 4=softplus(x+bias),
//      5=silu for cols n>=400 (in_proj z-half), 6=plain + bf16 side-copy of cols n<13 to C2
template <typename TC, int EPI>
__global__ __launch_bounds__(256) void gemm_mfma(const bf16* __restrict__ A, int lda,
                                                 const bf16* __restrict__ W,
                                                 const float* __restrict__ bias,
                                                 TC* __restrict__ C, int ldc,
                                                 bf16* __restrict__ C2, int ldc2,
                                                 int N, int K) {
    constexpr int LS = 40;                       // LDS row stride in shorts (32 + 8 pad, 80 B)
    __shared__ short As[128 * LS];
    __shared__ short Bs[128 * LS];
    const int m0 = blockIdx.x * 128;
    const int n0 = blockIdx.y * 128;
    const int tid = threadIdx.x;
    const int wave = tid >> 6;
    const int lane = tid & 63;
    const int wm = (wave & 1) * 64;
    const int wn = (wave >> 1) * 64;
    const int fm = lane & 15;
    const int quad = lane >> 4;

    f32x4 acc[4][4] = {};

    const int sr = tid >> 1;                     // staging row 0..127
    const int sc = (tid & 1) * 16;               // staging col 0 / 16

    for (int k0 = 0; k0 < K; k0 += 32) {
        // stage A: 128x32, 16 shorts/thread via 2x short8
        {
            const short* src = (const short*)A + (size_t)(m0 + sr) * lda + k0 + sc;
            short* dst = As + sr * LS + sc;
            if (k0 + sc + 16 <= K) {
                *(short8*)dst = *(const short8*)src;
                *(short8*)(dst + 8) = *(const short8*)(src + 8);
            } else {
#pragma unroll
                for (int j = 0; j < 16; ++j)
                    dst[j] = (k0 + sc + j < K) ? src[j] : (short)0;
            }
        }
        // stage B(W): 128x32, mask n and k
        {
            short* dst = Bs + sr * LS + sc;
            if (n0 + sr < N) {
                const short* src = (const short*)W + (size_t)(n0 + sr) * K + k0 + sc;
                if (k0 + sc + 16 <= K) {
                    *(short8*)dst = *(const short8*)src;
                    *(short8*)(dst + 8) = *(const short8*)(src + 8);
                } else {
#pragma unroll
                    for (int j = 0; j < 16; ++j)
                        dst[j] = (k0 + sc + j < K) ? src[j] : (short)0;
                }
            } else {
#pragma unroll
                for (int j = 0; j < 16; ++j) dst[j] = 0;
            }
        }
        __syncthreads();
        short8 af[4], bfr[4];
#pragma unroll
        for (int i = 0; i < 4; ++i)
            af[i] = *(const short8*)(As + (wm + i * 16 + fm) * LS + quad * 8);
#pragma unroll
        for (int j = 0; j < 4; ++j)
            bfr[j] = *(const short8*)(Bs + (wn + j * 16 + fm) * LS + quad * 8);
#pragma unroll
        for (int i = 0; i < 4; ++i)
#pragma unroll
            for (int j = 0; j < 4; ++j)
                acc[i][j] = __builtin_amdgcn_mfma_f32_16x16x32_bf16(af[i], bfr[j], acc[i][j], 0, 0, 0);
        __syncthreads();
    }

    // epilogue: D[m = quad*4 + r][n = fm] per 16x16 tile
#pragma unroll
    for (int j = 0; j < 4; ++j) {
        int n = n0 + wn + j * 16 + fm;
        if (n >= N) continue;
        float bv = (EPI == 2 || EPI == 3 || EPI == 4) ? bias[n] : 0.f;
#pragma unroll
        for (int i = 0; i < 4; ++i) {
#pragma unroll
            for (int r = 0; r < 4; ++r) {
                int m = m0 + wm + i * 16 + quad * 4 + r;
                float v = acc[i][j][r];
                if (EPI == 2) {
                    v += bv;
                    v = 0.5f * v * (1.f + erff(v * 0.70710678118654752f));
                } else if (EPI == 3) {
                    v += bv;
                } else if (EPI == 4) {
                    v += bv;
                    v = (v > 20.f) ? v : __logf(1.f + __expf(v));
                } else if (EPI == 5) {
                    if (n >= 400) v = v * __builtin_amdgcn_rcpf(1.f + __expf(-v));
                }
                stf(&C[(size_t)m * ldc + n], v);
                if (EPI == 6 && n < 13) C2[(size_t)m * ldc2 + n] = f2b(v);
            }
        }
    }
}

// ---------------- causal depthwise conv (k=4) + bias + silu, IN-PLACE on x-half ----------------
__global__ __launch_bounds__(256) void conv_silu_inplace(bf16* __restrict__ xz,
                                                         const float* __restrict__ cw,
                                                         const float* __restrict__ cb,
                                                         int total /* chunkB*DIE */) {
    int idx = blockIdx.x * 256 + threadIdx.x;
    if (idx >= total) return;
    int d = idx % DIE;
    int b = idx / DIE;
    float w0 = cw[d * 4 + 0];
    float w1 = cw[d * 4 + 1];
    float w2 = cw[d * 4 + 2];
    float w3 = cw[d * 4 + 3];
    float bias = cb[d];
    float x0 = 0.f, x1 = 0.f, x2 = 0.f;
    bf16* p = xz + (size_t)b * LSEQ * 800 + d;
    for (int t = 0; t < LSEQ; ++t) {
        float x = b2f(*p);
        float s = bias + w0 * x0 + w1 * x1 + w2 * x2 + w3 * x;
        x0 = x1; x1 = x2; x2 = x;
        float sig = __builtin_amdgcn_rcpf(1.f + __expf(-s));
        *p = f2b(s * sig);
        p += 800;
    }
}

// ---------------- fused selective scan: all per-step scalars precomputed / pipelined ----------
// sp (= softplus(dt@dtW+b)) precomputed by gemm_delta; silu(z) precomputed by gemm_in EPI5.
// Prefetch phase for step t+1 computes r=exp(-sp), dA power ladder, du — OFF the recurrence's
// critical path. Sequential chain per step is just h[n] = dA[n]*h[n] + du*B[n] (one FMA) plus
// a 4-accumulator y-tree.
// FAST: A[n] == -(n+1) (problem's A_log = log(1..16)) -> dA[n] = r^(n+1). Runtime-verified,
// generic fallback keeps correctness for arbitrary A.
template <bool FAST>
__device__ __forceinline__ void scan_body2(const float* __restrict__ rp,  // uniform B,C rows
                                           const float* __restrict__ spp, // per-lane, stride 400
                                           bf16* __restrict__ xp,         // per-lane, stride 800
                                           const float* A2, float Dv) {
    float h[16];
#pragma unroll
    for (int n = 0; n < 16; ++n) h[n] = 0.f;

    auto precomp = [&](int o45, int osp, int ox,
                       float* Bb, float* Cb, float* dA, float& du, float& ut, float& zs) {
#pragma unroll
        for (int j = 0; j < 16; ++j) { Bb[j] = rp[o45 + 13 + j]; Cb[j] = rp[o45 + 29 + j]; }
        float sp = spp[osp];
        ut = b2f(xp[ox]);
        zs = b2f(xp[ox + 400]);           // already silu(z)
        if (FAST) {
            float r1 = __expf(-sp);
            float r2 = r1 * r1, r3 = r2 * r1, r4 = r2 * r2;
            float r5 = r4 * r1, r6 = r4 * r2, r7 = r4 * r3, r8 = r4 * r4;
            dA[0] = r1;  dA[1] = r2;  dA[2] = r3;  dA[3] = r4;
            dA[4] = r5;  dA[5] = r6;  dA[6] = r7;  dA[7] = r8;
            dA[8] = r8 * r1;  dA[9] = r8 * r2;  dA[10] = r8 * r3;  dA[11] = r8 * r4;
            dA[12] = r8 * r5; dA[13] = r8 * r6; dA[14] = r8 * r7;  dA[15] = r8 * r8;
        } else {
#pragma unroll
            for (int n = 0; n < 16; ++n) dA[n] = __expf(sp * A2[n]);
        }
        du = sp * ut;
    };
    auto compute = [&](const float* Bb, const float* Cb, const float* dA,
                       float du, float ut, float zs, int ox) {
#pragma unroll
        for (int n = 0; n < 16; ++n) h[n] = dA[n] * h[n] + du * Bb[n];
        float y0 = 0.f, y1 = 0.f, y2 = 0.f, y3 = 0.f;
#pragma unroll
        for (int n = 0; n < 4; ++n) {
            y0 += h[n] * Cb[n];
            y1 += h[4 + n] * Cb[4 + n];
            y2 += h[8 + n] * Cb[8 + n];
            y3 += h[12 + n] * Cb[12 + n];
        }
        float yv = (y0 + y1) + (y2 + y3) + ut * Dv;
        xp[ox] = f2b(yv * zs);
    };

    float BA[16], CA[16], dAA[16], BB[16], CB[16], dAB[16];
    float duA, utA, zsA, duB, utB, zsB;

    precomp(0, 0, 0, BA, CA, dAA, duA, utA, zsA);

    for (int t = 0; t < LSEQ; t += 2) {
        precomp(45, 400, 800, BB, CB, dAB, duB, utB, zsB);      // t+1
        compute(BA, CA, dAA, duA, utA, zsA, 0);                 // t
        if (t + 2 < LSEQ)
            precomp(90, 800, 1600, BA, CA, dAA, duA, utA, zsA); // t+2
        compute(BB, CB, dAB, duB, utB, zsB, 800);               // t+1
        rp += 90; spp += 800; xp += 1600;
    }
}

__global__ __launch_bounds__(256) void scan_kernel(const float* __restrict__ xdbl,
                                                   const float* __restrict__ spbuf,
                                                   bf16* __restrict__ xz,
                                                   const float* __restrict__ A_log,
                                                   const float* __restrict__ Dw) {
    const int b = blockIdx.x >> 1;
    const int half = blockIdx.x & 1;
    const int tid = threadIdx.x;
    if (tid >= 200) return;            // no barriers below -> legal early exit
    const int d = half * 200 + tid;

    float A2[16];
    bool fast = true;
#pragma unroll
    for (int n = 0; n < 16; ++n) {
        A2[n] = -__expf(A_log[d * 16 + n]);
        fast = fast && (fabsf(A2[n] + (float)(n + 1)) < 1e-3f);
    }
    const float Dv = Dw[d];

    const float* __restrict__ rp  = xdbl + (size_t)b * LSEQ * 45;        // block-uniform
    const float* __restrict__ spp = spbuf + (size_t)b * LSEQ * 400 + d;  // per-lane
    bf16* __restrict__ xp = xz + (size_t)b * LSEQ * 800 + d;

    if (fast) scan_body2<true>(rp, spp, xp, A2, Dv);
    else      scan_body2<false>(rp, spp, xp, A2, Dv);
}

// ---------------- residual + layernorm over 200; emits f32 AND bf16 copies ----------------
// dstb is a DEDICATED bf16 buffer (no aliasing with xa/xb/dst except dst==xb same-row,
// which is safe: each row is read fully into registers by its owning wave before stores).
__global__ __launch_bounds__(256) void ln_res_kernel(const float* __restrict__ xa,
                                                     const float* xb,
                                                     const float* __restrict__ w,
                                                     const float* __restrict__ bias,
                                                     float* dst,
                                                     bf16* __restrict__ dstb, int rows) {
    int wave = threadIdx.x >> 6;
    int lane = threadIdx.x & 63;
    int row = blockIdx.x * 4 + wave;
    if (row >= rows) return;
    const float* pa = xa + (size_t)row * DM;
    const float* pb = xb + (size_t)row * DM;
    float v[4];
    float sum = 0.f, sq = 0.f;
#pragma unroll
    for (int i = 0; i < 4; ++i) {
        int c = lane + i * 64;
        float t = 0.f;
        if (c < DM) t = pa[c] + pb[c];
        v[i] = t;
        sum += t;
        sq += t * t;
    }
#pragma unroll
    for (int off = 32; off > 0; off >>= 1) {
        sum += __shfl_down(sum, off);
        sq += __shfl_down(sq, off);
    }
    sum = __shfl(sum, 0);
    sq = __shfl(sq, 0);
    float mu = sum * (1.f / DM);
    float var = fmaxf(sq * (1.f / DM) - mu * mu, 0.f);
    float rstd = rsqrtf(var + 1e-12f);
    float* pd = dst + (size_t)row * DM;
    bf16* pdb = dstb + (size_t)row * DM;
#pragma unroll
    for (int i = 0; i < 4; ++i) {
        int c = lane + i * 64;
        if (c < DM) {
            float o = (v[i] - mu) * rstd * w[c] + bias[c];
            pd[c] = o;
            pdb[c] = f2b(o);
        }
    }
}

// ---------------- output split for a batch chunk (f32 out) ----------------
__global__ __launch_bounds__(256) void write_out_kernel(const float* __restrict__ h,
                                                        float* __restrict__ out,
                                                        int b0, int total /* rc*DM */) {
    int idx = blockIdx.x * 256 + threadIdx.x;
    if (idx >= total) return;
    int d = idx % DM;
    int bl = idx / DM;
    int l = bl % LSEQ;
    int b = b0 + bl / LSEQ;
    float v = h[idx];
    if (l == LSEQ - 1) {
        out[b * DM + d] = v;
    } else {
        out[(size_t)NB * DM + ((size_t)(b * (LSEQ - 1) + l) * DM + d)] = v;
    }
}

extern "C" void kernel_launch(void* const* d_in, const int* in_sizes, int n_in,
                              void* d_out, int out_size, void* d_ws, size_t ws_size,
                              hipStream_t stream) {
    fp emb       = (fp)d_in[0];
    fp in_proj_w = (fp)d_in[2];
    fp conv_w    = (fp)d_in[3];
    fp conv_b    = (fp)d_in[4];
    fp x_proj_w  = (fp)d_in[5];
    fp dt_proj_w = (fp)d_in[6];
    fp dt_proj_b = (fp)d_in[7];
    fp A_log     = (fp)d_in[8];
    fp Dw        = (fp)d_in[9];
    fp out_proj_w= (fp)d_in[10];
    fp ln1_w     = (fp)d_in[11];
    fp ln1_b     = (fp)d_in[12];
    fp ffn_w1    = (fp)d_in[13];
    fp ffn_b1    = (fp)d_in[14];
    fp ffn_w2    = (fp)d_in[15];
    fp ffn_b2    = (fp)d_in[16];
    fp ffn_ln_w  = (fp)d_in[17];
    fp ffn_ln_b  = (fp)d_in[18];

    // workspace per-row bytes: xz 1600 + hb 400 + dtb 32 + sp 1600 + xdbl 180 + m 800 + h 800 = 5412
    const int cands[8] = {256, 128, 64, 32, 16, 8, 4, 2};
    int cb = 2;
    for (int ci = 0; ci < 8; ++ci) {
        size_t rcx = (size_t)cands[ci] * LSEQ;
        if (rcx * 5412 + W_BYTES + 1024 <= ws_size) { cb = cands[ci]; break; }
    }
    const size_t rc = (size_t)cb * LSEQ;

    bf16*  wb    = (bf16*)d_ws;                     // packed bf16 weights
    bf16*  xz    = (bf16*)((char*)d_ws + W_BYTES);  // rc*800 bf16
    bf16*  hb    = xz + rc * 800;                   // rc*200 bf16 (GEMM-A activation copy)
    bf16*  dtb   = hb + rc * 200;                   // rc*16 bf16 (dt cols for gemm_delta)
    float* spbuf = (float*)(dtb + rc * 16);         // rc*400 f32 (softplus(delta))
    float* xdbl  = spbuf + rc * 400;                // rc*45 f32
    float* m     = xdbl + rc * 45;                  // rc*200 f32
    float* h     = m + rc * 200;                    // rc*200 f32

    // pre-convert all GEMM weights to bf16 (once per launch)
    wcvt_kernel<<<(W_TOTAL / 4 + 255) / 256, 256, 0, stream>>>(
        in_proj_w, x_proj_w, out_proj_w, ffn_w1, ffn_w2, dt_proj_w, wb);

    const int rcDM = (int)rc * DM;
    const int gm = (int)rc / 128;              // m-tiles

    for (int b0 = 0; b0 < NB; b0 += cb) {
        const float* emb_chunk = emb + (size_t)b0 * LSEQ * DM;

        // emb chunk -> bf16 into hb
        cvt_kernel<<<(rcDM / 4 + 255) / 256, 256, 0, stream>>>(emb_chunk, hb, rcDM / 4);

        for (int i = 0; i < 2; ++i) {
            const bf16* wb_in = wb + (size_t)i * 160000;
            const bf16* wb_xp = wb + W_XP_OFF + (size_t)i * 18000;
            const bf16* wb_op = wb + W_OP_OFF + (size_t)i * 80000;
            const bf16* wb_f1 = wb + W_F1_OFF + (size_t)i * 160000;
            const bf16* wb_f2 = wb + W_F2_OFF + (size_t)i * 160000;
            const bf16* wb_dt = wb + W_DT_OFF + (size_t)i * 5200;
            fp cw    = conv_w + (size_t)i * 400 * 4;
            fp cbp   = conv_b + (size_t)i * 400;
            fp b_dt  = dt_proj_b + (size_t)i * 400;
            fp Ai    = A_log + (size_t)i * 400 * 16;
            fp Di    = Dw + (size_t)i * 400;
            fp l1w   = ln1_w + (size_t)i * 200;
            fp l1b   = ln1_b + (size_t)i * 200;
            fp f1b   = ffn_b1 + (size_t)i * 800;
            fp f2b_  = ffn_b2 + (size_t)i * 200;
            fp flw   = ffn_ln_w + (size_t)i * 200;
            fp flb   = ffn_ln_b + (size_t)i * 200;

            const float* hin = (i == 0) ? emb_chunk : h;   // f32 residual source

            // xz = hin @ in_proj^T (N=800, K=200); EPI5: z-half gets silu fused
            gemm_mfma<bf16, 5><<<dim3(gm, 7), 256, 0, stream>>>(
                hb, 200, wb_in, nullptr, xz, 800, nullptr, 0, 800, 200);
            // conv + silu in-place on x-half
            conv_silu_inplace<<<(cb * DIE + 255) / 256, 256, 0, stream>>>(xz, cw, cbp, cb * DIE);
            // xdbl = xc @ x_proj^T (N=45, K=400); EPI6: dt cols also stored bf16 -> dtb
            gemm_mfma<float, 6><<<dim3(gm, 1), 256, 0, stream>>>(
                xz, 800, wb_xp, nullptr, xdbl, 45, dtb, 16, 45, 400);
            // sp = softplus(dt @ dtW^T + b) (N=400, K=13)
            gemm_mfma<float, 4><<<dim3(gm, 4), 256, 0, stream>>>(
                dtb, 16, wb_dt, b_dt, spbuf, 400, nullptr, 0, 400, 13);
            // fused scan; y in-place on x-half
            scan_kernel<<<cb * 2, 256, 0, stream>>>(xdbl, spbuf, xz, Ai, Di);
            // m = y @ out_proj^T (N=200, K=400)
            gemm_mfma<float, 0><<<dim3(gm, 2), 256, 0, stream>>>(
                xz, 800, wb_op, nullptr, m, 200, nullptr, 0, 200, 400);
            // h = ln(m + hin), f32 into h + bf16 into hb
            ln_res_kernel<<<rc / 4, 256, 0, stream>>>(m, hin, l1w, l1b, h, hb, (int)rc);
            // f1 = gelu(h @ w1^T + b1) -> xz  (A = bf16 h in hb)
            gemm_mfma<bf16, 2><<<dim3(gm, 7), 256, 0, stream>>>(
                hb, 200, wb_f1, f1b, xz, 800, nullptr, 0, 800, 200);
            // f2 = f1 @ w2^T + b2 -> m (N=200, K=800)
            gemm_mfma<float, 3><<<dim3(gm, 2), 256, 0, stream>>>(
                xz, 800, wb_f2, f2b_, m, 200, nullptr, 0, 200, 800);
            // h = ln(f2 + h) in-place (same-row safe) + bf16 into hb (next layer's A)
            ln_res_kernel<<<rc / 4, 256, 0, stream>>>(m, h, flw, flb, h, hb, (int)rc);
        }

        write_out_kernel<<<rcDM / 256, 256, 0, stream>>>(h, (float*)d_out, b0, rcDM);
    }
}

// Round 5
// 1310.647 us; speedup vs baseline: 1.1558x; 1.1558x over previous
//
#include <hip/hip_runtime.h>
#include <hip/hip_bf16.h>

#define DM 200
#define DIE 400
#define LSEQ 256
#define NB 256

typedef __hip_bfloat16 bf16;
typedef const float* fp;
typedef __attribute__((ext_vector_type(8))) short short8;
typedef __attribute__((ext_vector_type(4))) short short4_t;
typedef __attribute__((ext_vector_type(4))) float f32x4;

__device__ __forceinline__ float b2f(bf16 x) { return __bfloat162float(x); }
__device__ __forceinline__ bf16  f2b(float x) { return __float2bfloat16(x); }

// f32 -> bf16 bits (round-to-nearest-even)
__device__ __forceinline__ unsigned short f2bbits(float f) {
    union { float f; unsigned int u; } c; c.f = f;
    unsigned int u = c.u;
    unsigned int r = (u + 0x7fffu + ((u >> 16) & 1u)) >> 16;
    return (unsigned short)r;
}
__device__ __forceinline__ void stf(float* p, float v) { *p = v; }
__device__ __forceinline__ void stf(bf16* p, float v) { *p = f2b(v); }

// ---------------- weight f32->bf16 pre-convert (5 arrays packed, both layers) ----------------
// float counts: in_proj 320000 | x_proj 36000 | out_proj 160000 | ffn1 320000 | ffn2 320000
#define W_XP_OFF 320000
#define W_OP_OFF 356000
#define W_F1_OFF 516000
#define W_F2_OFF 836000
#define W_TOTAL  1156000
#define W_BYTES  2312000

__global__ __launch_bounds__(256) void wcvt_kernel(fp a0, fp a1, fp a2, fp a3, fp a4,
                                                   bf16* __restrict__ dst) {
    int g = blockIdx.x * 256 + threadIdx.x;
    if (g >= W_TOTAL / 4) return;
    int idx = g * 4;
    const float* src;
    int off;
    if (idx < W_XP_OFF)      { src = a0; off = idx; }
    else if (idx < W_OP_OFF) { src = a1; off = idx - W_XP_OFF; }
    else if (idx < W_F1_OFF) { src = a2; off = idx - W_OP_OFF; }
    else if (idx < W_F2_OFF) { src = a3; off = idx - W_F1_OFF; }
    else                     { src = a4; off = idx - W_F2_OFF; }
    float4 v = *(const float4*)(src + off);
    short4_t o;
    o.x = (short)f2bbits(v.x); o.y = (short)f2bbits(v.y);
    o.z = (short)f2bbits(v.z); o.w = (short)f2bbits(v.w);
    *(short4_t*)((short*)dst + idx) = o;
}

// ---------------- generic f32 -> bf16 convert (for emb chunk) ----------------
__global__ __launch_bounds__(256) void cvt_kernel(const float* __restrict__ src,
                                                  bf16* __restrict__ dst, int n4) {
    int g = blockIdx.x * 256 + threadIdx.x;
    if (g >= n4) return;
    int idx = g * 4;
    float4 v = *(const float4*)(src + idx);
    short4_t o;
    o.x = (short)f2bbits(v.x); o.y = (short)f2bbits(v.y);
    o.z = (short)f2bbits(v.z); o.w = (short)f2bbits(v.w);
    *(short4_t*)((short*)dst + idx) = o;
}

// ---------------- MFMA NT GEMM: C[m,n] = sum_k A[m,k]*W[n,k] (+epilogue) ----------------
// A and W both bf16 in memory -> staging is pure short8 vector loads (no convert).
// Block tile 128(m) x 128(n), K-step 32, 4 waves in 2x2; wave subtile 64x64 = 4x4 MFMA tiles.
// EPI: 0=none, 2=gelu_exact(x+bias), 3=x+bias, 5=silu for cols n>=400 (in_proj z-half)
template <typename TC, int EPI>
__global__ __launch_bounds__(256) void gemm_mfma(const bf16* __restrict__ A, int lda,
                                                 const bf16* __restrict__ W,
                                                 const float* __restrict__ bias,
                                                 TC* __restrict__ C, int ldc,
                                                 int N, int K) {
    constexpr int LS = 40;                       // LDS row stride in shorts (32 + 8 pad, 80 B)
    __shared__ short As[128 * LS];
    __shared__ short Bs[128 * LS];
    const int m0 = blockIdx.x * 128;
    const int n0 = blockIdx.y * 128;
    const int tid = threadIdx.x;
    const int wave = tid >> 6;
    const int lane = tid & 63;
    const int wm = (wave & 1) * 64;
    const int wn = (wave >> 1) * 64;
    const int fm = lane & 15;
    const int quad = lane >> 4;

    f32x4 acc[4][4] = {};

    const int sr = tid >> 1;                     // staging row 0..127
    const int sc = (tid & 1) * 16;               // staging col 0 / 16

    for (int k0 = 0; k0 < K; k0 += 32) {
        // stage A: 128x32, 16 shorts/thread via 2x short8
        {
            const short* src = (const short*)A + (size_t)(m0 + sr) * lda + k0 + sc;
            short* dst = As + sr * LS + sc;
            if (k0 + sc + 16 <= K) {
                *(short8*)dst = *(const short8*)src;
                *(short8*)(dst + 8) = *(const short8*)(src + 8);
            } else {
#pragma unroll
                for (int j = 0; j < 16; ++j)
                    dst[j] = (k0 + sc + j < K) ? src[j] : (short)0;
            }
        }
        // stage B(W): 128x32, mask n and k
        {
            short* dst = Bs + sr * LS + sc;
            if (n0 + sr < N) {
                const short* src = (const short*)W + (size_t)(n0 + sr) * K + k0 + sc;
                if (k0 + sc + 16 <= K) {
                    *(short8*)dst = *(const short8*)src;
                    *(short8*)(dst + 8) = *(const short8*)(src + 8);
                } else {
#pragma unroll
                    for (int j = 0; j < 16; ++j)
                        dst[j] = (k0 + sc + j < K) ? src[j] : (short)0;
                }
            } else {
#pragma unroll
                for (int j = 0; j < 16; ++j) dst[j] = 0;
            }
        }
        __syncthreads();
        short8 af[4], bfr[4];
#pragma unroll
        for (int i = 0; i < 4; ++i)
            af[i] = *(const short8*)(As + (wm + i * 16 + fm) * LS + quad * 8);
#pragma unroll
        for (int j = 0; j < 4; ++j)
            bfr[j] = *(const short8*)(Bs + (wn + j * 16 + fm) * LS + quad * 8);
#pragma unroll
        for (int i = 0; i < 4; ++i)
#pragma unroll
            for (int j = 0; j < 4; ++j)
                acc[i][j] = __builtin_amdgcn_mfma_f32_16x16x32_bf16(af[i], bfr[j], acc[i][j], 0, 0, 0);
        __syncthreads();
    }

    // epilogue: D[m = quad*4 + r][n = fm] per 16x16 tile
#pragma unroll
    for (int j = 0; j < 4; ++j) {
        int n = n0 + wn + j * 16 + fm;
        if (n >= N) continue;
        float bv = (EPI == 2 || EPI == 3) ? bias[n] : 0.f;
#pragma unroll
        for (int i = 0; i < 4; ++i) {
#pragma unroll
            for (int r = 0; r < 4; ++r) {
                int m = m0 + wm + i * 16 + quad * 4 + r;
                float v = acc[i][j][r];
                if (EPI == 2) {
                    v += bv;
                    v = 0.5f * v * (1.f + erff(v * 0.70710678118654752f));
                } else if (EPI == 3) {
                    v += bv;
                } else if (EPI == 5) {
                    if (n >= 400) v = v * __builtin_amdgcn_rcpf(1.f + __expf(-v));
                }
                stf(&C[(size_t)m * ldc + n], v);
            }
        }
    }
}

// ---------------- causal depthwise conv (k=4) + bias + silu, IN-PLACE on x-half ----------------
__global__ __launch_bounds__(256) void conv_silu_inplace(bf16* __restrict__ xz,
                                                         const float* __restrict__ cw,
                                                         const float* __restrict__ cb,
                                                         int total /* chunkB*DIE */) {
    int idx = blockIdx.x * 256 + threadIdx.x;
    if (idx >= total) return;
    int d = idx % DIE;
    int b = idx / DIE;
    float w0 = cw[d * 4 + 0];
    float w1 = cw[d * 4 + 1];
    float w2 = cw[d * 4 + 2];
    float w3 = cw[d * 4 + 3];
    float bias = cb[d];
    float x0 = 0.f, x1 = 0.f, x2 = 0.f;
    bf16* p = xz + (size_t)b * LSEQ * 800 + d;
    for (int t = 0; t < LSEQ; ++t) {
        float x = b2f(*p);
        float s = bias + w0 * x0 + w1 * x1 + w2 * x2 + w3 * x;
        x0 = x1; x1 = x2; x2 = x;
        float sig = __builtin_amdgcn_rcpf(1.f + __expf(-s));
        *p = f2b(s * sig);
        p += 800;
    }
}

// ---------------- fused selective scan, barrier-free, ping-pong pipelined ----------------
// z is already silu'd (gemm_in EPI5). All feed-forward work (dt-dot, softplus, dA ladder, du)
// sits in the prefetch phase; the sequential chain is just h[n] = dA[n]*h[n] + du*B[n]
// plus a 4-accumulator y-tree. No 45-elem rotate (ping-pong buffers instead).
// FAST: A[n] == -(n+1) (problem's A_log = log(1..16)) -> dA[n] = r^(n+1), r = exp(-sp).
// Runtime-verified per thread, generic fallback keeps correctness for arbitrary A.
template <bool FAST>
__device__ __forceinline__ void scan_body(const float* __restrict__ rp,  // uniform rows (45)
                                          bf16* __restrict__ xp,         // per-lane, stride 800
                                          const float* Wr, const float* A2,
                                          float bdt, float Dv) {
    float h[16];
#pragma unroll
    for (int n = 0; n < 16; ++n) h[n] = 0.f;

    auto precomp = [&](int o45, int ox,
                       float* Bb, float* Cb, float* dA, float& du, float& ut, float& zs) {
        float dtv = bdt;
#pragma unroll
        for (int r = 0; r < 13; ++r) dtv += Wr[r] * rp[o45 + r];
#pragma unroll
        for (int j = 0; j < 16; ++j) { Bb[j] = rp[o45 + 13 + j]; Cb[j] = rp[o45 + 29 + j]; }
        ut = b2f(xp[ox]);
        zs = b2f(xp[ox + 400]);           // already silu(z)
        float sp = (dtv > 20.f) ? dtv : __logf(1.f + __expf(dtv));
        if (FAST) {
            float r1 = __expf(-sp);
            float r2 = r1 * r1, r3 = r2 * r1, r4 = r2 * r2;
            float r5 = r4 * r1, r6 = r4 * r2, r7 = r4 * r3, r8 = r4 * r4;
            dA[0] = r1;  dA[1] = r2;  dA[2] = r3;  dA[3] = r4;
            dA[4] = r5;  dA[5] = r6;  dA[6] = r7;  dA[7] = r8;
            dA[8] = r8 * r1;  dA[9] = r8 * r2;  dA[10] = r8 * r3;  dA[11] = r8 * r4;
            dA[12] = r8 * r5; dA[13] = r8 * r6; dA[14] = r8 * r7;  dA[15] = r8 * r8;
        } else {
#pragma unroll
            for (int n = 0; n < 16; ++n) dA[n] = __expf(sp * A2[n]);
        }
        du = sp * ut;
    };
    auto compute = [&](const float* Bb, const float* Cb, const float* dA,
                       float du, float ut, float zs, int ox) {
#pragma unroll
        for (int n = 0; n < 16; ++n) h[n] = dA[n] * h[n] + du * Bb[n];
        float y0 = 0.f, y1 = 0.f, y2 = 0.f, y3 = 0.f;
#pragma unroll
        for (int n = 0; n < 4; ++n) {
            y0 += h[n] * Cb[n];
            y1 += h[4 + n] * Cb[4 + n];
            y2 += h[8 + n] * Cb[8 + n];
            y3 += h[12 + n] * Cb[12 + n];
        }
        float yv = (y0 + y1) + (y2 + y3) + ut * Dv;
        xp[ox] = f2b(yv * zs);
    };

    float BA[16], CA[16], dAA[16], BB[16], CB[16], dAB[16];
    float duA, utA, zsA, duB, utB, zsB;

    precomp(0, 0, BA, CA, dAA, duA, utA, zsA);

    for (int t = 0; t < LSEQ; t += 2) {
        precomp(45, 800, BB, CB, dAB, duB, utB, zsB);      // t+1
        compute(BA, CA, dAA, duA, utA, zsA, 0);            // t
        if (t + 2 < LSEQ)
            precomp(90, 1600, BA, CA, dAA, duA, utA, zsA); // t+2
        compute(BB, CB, dAB, duB, utB, zsB, 800);          // t+1
        rp += 90; xp += 1600;
    }
}

__global__ __launch_bounds__(256) void scan_kernel(const float* __restrict__ xdbl,
                                                   bf16* __restrict__ xz,
                                                   const float* __restrict__ dt_w,
                                                   const float* __restrict__ dt_b,
                                                   const float* __restrict__ A_log,
                                                   const float* __restrict__ Dw) {
    const int b = blockIdx.x >> 1;
    const int half = blockIdx.x & 1;
    const int tid = threadIdx.x;
    if (tid >= 200) return;            // no barriers below -> legal early exit
    const int d = half * 200 + tid;

    float A2[16], Wr[13];
    bool fast = true;
#pragma unroll
    for (int n = 0; n < 16; ++n) {
        A2[n] = -__expf(A_log[d * 16 + n]);
        fast = fast && (fabsf(A2[n] + (float)(n + 1)) < 1e-3f);
    }
#pragma unroll
    for (int r = 0; r < 13; ++r) Wr[r] = dt_w[d * 13 + r];
    const float bdt = dt_b[d];
    const float Dv = Dw[d];

    const float* __restrict__ rp = xdbl + (size_t)b * LSEQ * 45;   // block-uniform
    bf16* __restrict__ xp = xz + (size_t)b * LSEQ * 800 + d;

    if (fast) scan_body<true>(rp, xp, Wr, A2, bdt, Dv);
    else      scan_body<false>(rp, xp, Wr, A2, bdt, Dv);
}

// ---------------- residual + layernorm over 200 ----------------
// Normal mode (outp == nullptr): writes f32 to dst and bf16 copy to dstb (dedicated buffer;
// dst==xb same-row in-place is safe: full row read into regs before any store).
// Final mode (outp != nullptr): writes ONLY the scattered output (c-slot for l==LSEQ-1,
// x_n slot otherwise) -- fuses the old write_out pass.
__global__ __launch_bounds__(256) void ln_res_kernel(const float* __restrict__ xa,
                                                     const float* xb,
                                                     const float* __restrict__ w,
                                                     const float* __restrict__ bias,
                                                     float* dst,
                                                     bf16* __restrict__ dstb, int rows,
                                                     float* __restrict__ outp, int b0) {
    int wave = threadIdx.x >> 6;
    int lane = threadIdx.x & 63;
    int row = blockIdx.x * 4 + wave;
    if (row >= rows) return;
    const float* pa = xa + (size_t)row * DM;
    const float* pb = xb + (size_t)row * DM;
    float v[4];
    float sum = 0.f, sq = 0.f;
#pragma unroll
    for (int i = 0; i < 4; ++i) {
        int c = lane + i * 64;
        float t = 0.f;
        if (c < DM) t = pa[c] + pb[c];
        v[i] = t;
        sum += t;
        sq += t * t;
    }
#pragma unroll
    for (int off = 32; off > 0; off >>= 1) {
        sum += __shfl_down(sum, off);
        sq += __shfl_down(sq, off);
    }
    sum = __shfl(sum, 0);
    sq = __shfl(sq, 0);
    float mu = sum * (1.f / DM);
    float var = fmaxf(sq * (1.f / DM) - mu * mu, 0.f);
    float rstd = rsqrtf(var + 1e-12f);
    if (outp) {
        int bb = b0 + row / LSEQ;
        int l = row % LSEQ;
        float* po = (l == LSEQ - 1)
                        ? outp + (size_t)bb * DM
                        : outp + (size_t)NB * DM + (size_t)(bb * (LSEQ - 1) + l) * DM;
#pragma unroll
        for (int i = 0; i < 4; ++i) {
            int c = lane + i * 64;
            if (c < DM) po[c] = (v[i] - mu) * rstd * w[c] + bias[c];
        }
    } else {
        float* pd = dst + (size_t)row * DM;
        bf16* pdb = dstb + (size_t)row * DM;
#pragma unroll
        for (int i = 0; i < 4; ++i) {
            int c = lane + i * 64;
            if (c < DM) {
                float o = (v[i] - mu) * rstd * w[c] + bias[c];
                pd[c] = o;
                pdb[c] = f2b(o);
            }
        }
    }
}

extern "C" void kernel_launch(void* const* d_in, const int* in_sizes, int n_in,
                              void* d_out, int out_size, void* d_ws, size_t ws_size,
                              hipStream_t stream) {
    fp emb       = (fp)d_in[0];
    fp in_proj_w = (fp)d_in[2];
    fp conv_w    = (fp)d_in[3];
    fp conv_b    = (fp)d_in[4];
    fp x_proj_w  = (fp)d_in[5];
    fp dt_proj_w = (fp)d_in[6];
    fp dt_proj_b = (fp)d_in[7];
    fp A_log     = (fp)d_in[8];
    fp Dw        = (fp)d_in[9];
    fp out_proj_w= (fp)d_in[10];
    fp ln1_w     = (fp)d_in[11];
    fp ln1_b     = (fp)d_in[12];
    fp ffn_w1    = (fp)d_in[13];
    fp ffn_b1    = (fp)d_in[14];
    fp ffn_w2    = (fp)d_in[15];
    fp ffn_b2    = (fp)d_in[16];
    fp ffn_ln_w  = (fp)d_in[17];
    fp ffn_ln_b  = (fp)d_in[18];

    // workspace per-row bytes: xz 1600 + hb 400 + xdbl 180 + m 800 + h 800 = 3780  (R3 budget)
    const int cands[8] = {256, 128, 64, 32, 16, 8, 4, 2};
    int cb = 2;
    for (int ci = 0; ci < 8; ++ci) {
        size_t rcx = (size_t)cands[ci] * LSEQ;
        if (rcx * 3780 + W_BYTES + 1024 <= ws_size) { cb = cands[ci]; break; }
    }
    const size_t rc = (size_t)cb * LSEQ;

    bf16*  wb   = (bf16*)d_ws;                     // packed bf16 weights
    bf16*  xz   = (bf16*)((char*)d_ws + W_BYTES);  // rc*800 bf16
    bf16*  hb   = xz + rc * 800;                   // rc*200 bf16 (GEMM-A activation copy)
    float* xdbl = (float*)(hb + rc * 200);         // rc*45 f32
    float* m    = xdbl + rc * 45;                  // rc*200 f32
    float* h    = m + rc * 200;                    // rc*200 f32

    // pre-convert all GEMM weights to bf16 (once per launch)
    wcvt_kernel<<<(W_TOTAL / 4 + 255) / 256, 256, 0, stream>>>(
        in_proj_w, x_proj_w, out_proj_w, ffn_w1, ffn_w2, wb);

    const int rcDM = (int)rc * DM;
    const int gm = (int)rc / 128;              // m-tiles

    for (int b0 = 0; b0 < NB; b0 += cb) {
        const float* emb_chunk = emb + (size_t)b0 * LSEQ * DM;

        // emb chunk -> bf16 into hb
        cvt_kernel<<<(rcDM / 4 + 255) / 256, 256, 0, stream>>>(emb_chunk, hb, rcDM / 4);

        for (int i = 0; i < 2; ++i) {
            const bf16* wb_in = wb + (size_t)i * 160000;
            const bf16* wb_xp = wb + W_XP_OFF + (size_t)i * 18000;
            const bf16* wb_op = wb + W_OP_OFF + (size_t)i * 80000;
            const bf16* wb_f1 = wb + W_F1_OFF + (size_t)i * 160000;
            const bf16* wb_f2 = wb + W_F2_OFF + (size_t)i * 160000;
            fp cw    = conv_w + (size_t)i * 400 * 4;
            fp cbp   = conv_b + (size_t)i * 400;
            fp w_dt  = dt_proj_w + (size_t)i * 400 * 13;
            fp b_dt  = dt_proj_b + (size_t)i * 400;
            fp Ai    = A_log + (size_t)i * 400 * 16;
            fp Di    = Dw + (size_t)i * 400;
            fp l1w   = ln1_w + (size_t)i * 200;
            fp l1b   = ln1_b + (size_t)i * 200;
            fp f1b   = ffn_b1 + (size_t)i * 800;
            fp f2b_  = ffn_b2 + (size_t)i * 200;
            fp flw   = ffn_ln_w + (size_t)i * 200;
            fp flb   = ffn_ln_b + (size_t)i * 200;

            const float* hin = (i == 0) ? emb_chunk : h;   // f32 residual source
            const bool last = (i == 1);

            // xz = hin @ in_proj^T (N=800, K=200); EPI5: z-half gets silu fused
            gemm_mfma<bf16, 5><<<dim3(gm, 7), 256, 0, stream>>>(
                hb, 200, wb_in, nullptr, xz, 800, 800, 200);
            // conv + silu in-place on x-half
            conv_silu_inplace<<<(cb * DIE + 255) / 256, 256, 0, stream>>>(xz, cw, cbp, cb * DIE);
            // xdbl = xc @ x_proj^T (N=45, K=400)
            gemm_mfma<float, 0><<<dim3(gm, 1), 256, 0, stream>>>(
                xz, 800, wb_xp, nullptr, xdbl, 45, 45, 400);
            // fused scan; y in-place on x-half
            scan_kernel<<<cb * 2, 256, 0, stream>>>(xdbl, xz, w_dt, b_dt, Ai, Di);
            // m = y @ out_proj^T (N=200, K=400)
            gemm_mfma<float, 0><<<dim3(gm, 2), 256, 0, stream>>>(
                xz, 800, wb_op, nullptr, m, 200, 200, 400);
            // h = ln(m + hin), f32 into h + bf16 into hb
            ln_res_kernel<<<rc / 4, 256, 0, stream>>>(m, hin, l1w, l1b, h, hb, (int)rc,
                                                      nullptr, 0);
            // f1 = gelu(h @ w1^T + b1) -> xz  (A = bf16 h in hb)
            gemm_mfma<bf16, 2><<<dim3(gm, 7), 256, 0, stream>>>(
                hb, 200, wb_f1, f1b, xz, 800, 800, 200);
            // f2 = f1 @ w2^T + b2 -> m (N=200, K=800)
            gemm_mfma<float, 3><<<dim3(gm, 2), 256, 0, stream>>>(
                xz, 800, wb_f2, f2b_, m, 200, 200, 800);
            // h = ln(f2 + h); final layer writes the scattered output directly
            ln_res_kernel<<<rc / 4, 256, 0, stream>>>(m, h, flw, flb, h, hb, (int)rc,
                                                      last ? (float*)d_out : nullptr, b0);
        }
    }
}

// Round 6
// 1306.517 us; speedup vs baseline: 1.1595x; 1.0032x over previous
//
#include <hip/hip_runtime.h>
#include <hip/hip_bf16.h>

#define DM 200
#define DIE 400
#define LSEQ 256
#define NB 256

typedef __hip_bfloat16 bf16;
typedef const float* fp;
typedef __attribute__((ext_vector_type(8))) short short8;
typedef __attribute__((ext_vector_type(4))) short short4_t;
typedef __attribute__((ext_vector_type(4))) float f32x4;

__device__ __forceinline__ float b2f(bf16 x) { return __bfloat162float(x); }
__device__ __forceinline__ bf16  f2b(float x) { return __float2bfloat16(x); }

// f32 -> bf16 bits (round-to-nearest-even)
__device__ __forceinline__ unsigned short f2bbits(float f) {
    union { float f; unsigned int u; } c; c.f = f;
    unsigned int u = c.u;
    unsigned int r = (u + 0x7fffu + ((u >> 16) & 1u)) >> 16;
    return (unsigned short)r;
}
__device__ __forceinline__ void stf(float* p, float v) { *p = v; }
__device__ __forceinline__ void stf(bf16* p, float v) { *p = f2b(v); }

// ---------------- weight f32->bf16 pre-convert (5 arrays packed, both layers) ----------------
// float counts: in_proj 320000 | x_proj 36000 | out_proj 160000 | ffn1 320000 | ffn2 320000
#define W_XP_OFF 320000
#define W_OP_OFF 356000
#define W_F1_OFF 516000
#define W_F2_OFF 836000
#define W_TOTAL  1156000
#define W_BYTES  2312000

__global__ __launch_bounds__(256) void wcvt_kernel(fp a0, fp a1, fp a2, fp a3, fp a4,
                                                   bf16* __restrict__ dst) {
    int g = blockIdx.x * 256 + threadIdx.x;
    if (g >= W_TOTAL / 4) return;
    int idx = g * 4;
    const float* src;
    int off;
    if (idx < W_XP_OFF)      { src = a0; off = idx; }
    else if (idx < W_OP_OFF) { src = a1; off = idx - W_XP_OFF; }
    else if (idx < W_F1_OFF) { src = a2; off = idx - W_OP_OFF; }
    else if (idx < W_F2_OFF) { src = a3; off = idx - W_F1_OFF; }
    else                     { src = a4; off = idx - W_F2_OFF; }
    float4 v = *(const float4*)(src + off);
    short4_t o;
    o.x = (short)f2bbits(v.x); o.y = (short)f2bbits(v.y);
    o.z = (short)f2bbits(v.z); o.w = (short)f2bbits(v.w);
    *(short4_t*)((short*)dst + idx) = o;
}

// ---------------- generic f32 -> bf16 convert (for emb chunk) ----------------
__global__ __launch_bounds__(256) void cvt_kernel(const float* __restrict__ src,
                                                  bf16* __restrict__ dst, int n4) {
    int g = blockIdx.x * 256 + threadIdx.x;
    if (g >= n4) return;
    int idx = g * 4;
    float4 v = *(const float4*)(src + idx);
    short4_t o;
    o.x = (short)f2bbits(v.x); o.y = (short)f2bbits(v.y);
    o.z = (short)f2bbits(v.z); o.w = (short)f2bbits(v.w);
    *(short4_t*)((short*)dst + idx) = o;
}

// ---------------- MFMA NT GEMM: C[m,n] = sum_k A[m,k]*W[n,k] (+epilogue) ----------------
// A and W both bf16 in memory -> staging is pure short8 vector loads (no convert).
// Block tile 128(m) x 128(n), K-step 32, 4 waves in 2x2; wave subtile 64x64 = 4x4 MFMA tiles.
// EPI: 0=none, 2=gelu_exact(x+bias), 3=x+bias, 5=silu for cols n>=400 (in_proj z-half)
template <typename TC, int EPI>
__global__ __launch_bounds__(256) void gemm_mfma(const bf16* __restrict__ A, int lda,
                                                 const bf16* __restrict__ W,
                                                 const float* __restrict__ bias,
                                                 TC* __restrict__ C, int ldc,
                                                 int N, int K) {
    constexpr int LS = 40;                       // LDS row stride in shorts (32 + 8 pad, 80 B)
    __shared__ short As[128 * LS];
    __shared__ short Bs[128 * LS];
    const int m0 = blockIdx.x * 128;
    const int n0 = blockIdx.y * 128;
    const int tid = threadIdx.x;
    const int wave = tid >> 6;
    const int lane = tid & 63;
    const int wm = (wave & 1) * 64;
    const int wn = (wave >> 1) * 64;
    const int fm = lane & 15;
    const int quad = lane >> 4;

    f32x4 acc[4][4] = {};

    const int sr = tid >> 1;                     // staging row 0..127
    const int sc = (tid & 1) * 16;               // staging col 0 / 16

    for (int k0 = 0; k0 < K; k0 += 32) {
        // stage A: 128x32, 16 shorts/thread via 2x short8
        {
            const short* src = (const short*)A + (size_t)(m0 + sr) * lda + k0 + sc;
            short* dst = As + sr * LS + sc;
            if (k0 + sc + 16 <= K) {
                *(short8*)dst = *(const short8*)src;
                *(short8*)(dst + 8) = *(const short8*)(src + 8);
            } else {
#pragma unroll
                for (int j = 0; j < 16; ++j)
                    dst[j] = (k0 + sc + j < K) ? src[j] : (short)0;
            }
        }
        // stage B(W): 128x32, mask n and k
        {
            short* dst = Bs + sr * LS + sc;
            if (n0 + sr < N) {
                const short* src = (const short*)W + (size_t)(n0 + sr) * K + k0 + sc;
                if (k0 + sc + 16 <= K) {
                    *(short8*)dst = *(const short8*)src;
                    *(short8*)(dst + 8) = *(const short8*)(src + 8);
                } else {
#pragma unroll
                    for (int j = 0; j < 16; ++j)
                        dst[j] = (k0 + sc + j < K) ? src[j] : (short)0;
                }
            } else {
#pragma unroll
                for (int j = 0; j < 16; ++j) dst[j] = 0;
            }
        }
        __syncthreads();
        short8 af[4], bfr[4];
#pragma unroll
        for (int i = 0; i < 4; ++i)
            af[i] = *(const short8*)(As + (wm + i * 16 + fm) * LS + quad * 8);
#pragma unroll
        for (int j = 0; j < 4; ++j)
            bfr[j] = *(const short8*)(Bs + (wn + j * 16 + fm) * LS + quad * 8);
#pragma unroll
        for (int i = 0; i < 4; ++i)
#pragma unroll
            for (int j = 0; j < 4; ++j)
                acc[i][j] = __builtin_amdgcn_mfma_f32_16x16x32_bf16(af[i], bfr[j], acc[i][j], 0, 0, 0);
        __syncthreads();
    }

    // epilogue: D[m = quad*4 + r][n = fm] per 16x16 tile
#pragma unroll
    for (int j = 0; j < 4; ++j) {
        int n = n0 + wn + j * 16 + fm;
        if (n >= N) continue;
        float bv = (EPI == 2 || EPI == 3) ? bias[n] : 0.f;
#pragma unroll
        for (int i = 0; i < 4; ++i) {
#pragma unroll
            for (int r = 0; r < 4; ++r) {
                int m = m0 + wm + i * 16 + quad * 4 + r;
                float v = acc[i][j][r];
                if (EPI == 2) {
                    v += bv;
                    v = 0.5f * v * (1.f + erff(v * 0.70710678118654752f));
                } else if (EPI == 3) {
                    v += bv;
                } else if (EPI == 5) {
                    if (n >= 400) v = v * __builtin_amdgcn_rcpf(1.f + __expf(-v));
                }
                stf(&C[(size_t)m * ldc + n], v);
            }
        }
    }
}

// ---------------- causal depthwise conv (k=4) + bias + silu, IN-PLACE on x-half ----------------
__global__ __launch_bounds__(256) void conv_silu_inplace(bf16* __restrict__ xz,
                                                         const float* __restrict__ cw,
                                                         const float* __restrict__ cb,
                                                         int total /* chunkB*DIE */) {
    int idx = blockIdx.x * 256 + threadIdx.x;
    if (idx >= total) return;
    int d = idx % DIE;
    int b = idx / DIE;
    float w0 = cw[d * 4 + 0];
    float w1 = cw[d * 4 + 1];
    float w2 = cw[d * 4 + 2];
    float w3 = cw[d * 4 + 3];
    float bias = cb[d];
    float x0 = 0.f, x1 = 0.f, x2 = 0.f;
    bf16* p = xz + (size_t)b * LSEQ * 800 + d;
    for (int t = 0; t < LSEQ; ++t) {
        float x = b2f(*p);
        float s = bias + w0 * x0 + w1 * x1 + w2 * x2 + w3 * x;
        x0 = x1; x1 = x2; x2 = x;
        float sig = __builtin_amdgcn_rcpf(1.f + __expf(-s));
        *p = f2b(s * sig);
        p += 800;
    }
}

// ---------------- fused selective scan: 2 lanes per channel (8 states each) ----------------
// Lanes (2k,2k+1) share channel d=k: each holds h[8], loads 8 B/C values; the y-dot is
// finished with one __shfl_xor. Doubles active waves (latency hiding) and halves per-wave
// per-step work. dt-dot/softplus/ladder duplicated per pair (feed-forward, cheap).
// z is already silu'd (gemm_in EPI5). Ping-pong prefetch: step t+1's feed-forward work
// overlaps step t's recurrence.
// FAST: A[n] == -(n+1) (problem's A_log = log(1..16)) -> dA[n] = r^(n+1), r = exp(-sp).
// Runtime-verified per thread, generic fallback keeps correctness for arbitrary A.
template <bool FAST>
__device__ __forceinline__ void scan_body(const float* __restrict__ rp,  // uniform rows (45)
                                          bf16* __restrict__ xp,         // at elem d, stride 800
                                          const float* Wr, const float* A2, // 8 entries
                                          float bdt, float Dv, int sub) {
    float h[8];
#pragma unroll
    for (int n = 0; n < 8; ++n) h[n] = 0.f;
    const int nbase = 13 + sub * 8;
    const int cbase = 29 + sub * 8;

    auto precomp = [&](int o45, int ox,
                       float* Bb, float* Cb, float* dA, float& du, float& ut, float& zs) {
        float dtv = bdt;
#pragma unroll
        for (int r = 0; r < 13; ++r) dtv += Wr[r] * rp[o45 + r];
#pragma unroll
        for (int j = 0; j < 8; ++j) { Bb[j] = rp[o45 + nbase + j]; Cb[j] = rp[o45 + cbase + j]; }
        ut = b2f(xp[ox]);
        zs = b2f(xp[ox + 400]);           // already silu(z)
        float sp = (dtv > 20.f) ? dtv : __logf(1.f + __expf(dtv));
        if (FAST) {
            float r1 = __expf(-sp);
            float r2 = r1 * r1, r3 = r2 * r1, r4 = r2 * r2;
            float r5 = r4 * r1, r6 = r4 * r2, r7 = r4 * r3, r8 = r4 * r4;
            float m8 = sub ? r8 : 1.f;
            dA[0] = r1 * m8; dA[1] = r2 * m8; dA[2] = r3 * m8; dA[3] = r4 * m8;
            dA[4] = r5 * m8; dA[5] = r6 * m8; dA[6] = r7 * m8; dA[7] = r8 * m8;
        } else {
#pragma unroll
            for (int n = 0; n < 8; ++n) dA[n] = __expf(sp * A2[n]);
        }
        du = sp * ut;
    };
    auto compute = [&](const float* Bb, const float* Cb, const float* dA,
                       float du, float ut, float zs, int ox) {
#pragma unroll
        for (int n = 0; n < 8; ++n) h[n] = dA[n] * h[n] + du * Bb[n];
        float y0 = 0.f, y1 = 0.f;
#pragma unroll
        for (int n = 0; n < 4; ++n) {
            y0 += h[n] * Cb[n];
            y1 += h[4 + n] * Cb[4 + n];
        }
        float y = y0 + y1;
        y += __shfl_xor(y, 1);            // pair-sum across the two sub-lanes
        if (sub == 0) {
            float yv = y + ut * Dv;
            xp[ox] = f2b(yv * zs);
        }
    };

    float BA[8], CA[8], dAA[8], BB[8], CB[8], dAB[8];
    float duA, utA, zsA, duB, utB, zsB;

    precomp(0, 0, BA, CA, dAA, duA, utA, zsA);

    for (int t = 0; t < LSEQ; t += 2) {
        precomp(45, 800, BB, CB, dAB, duB, utB, zsB);      // t+1
        compute(BA, CA, dAA, duA, utA, zsA, 0);            // t
        if (t + 2 < LSEQ)
            precomp(90, 1600, BA, CA, dAA, duA, utA, zsA); // t+2
        compute(BB, CB, dAB, duB, utB, zsB, 800);          // t+1
        rp += 90; xp += 1600;
    }
}

__global__ __launch_bounds__(512) void scan_kernel(const float* __restrict__ xdbl,
                                                   bf16* __restrict__ xz,
                                                   const float* __restrict__ dt_w,
                                                   const float* __restrict__ dt_b,
                                                   const float* __restrict__ A_log,
                                                   const float* __restrict__ Dw) {
    const int b = blockIdx.x >> 1;
    const int half = blockIdx.x & 1;
    const int tid = threadIdx.x;
    if (tid >= 400) return;            // no barriers below -> legal early exit
    const int d = half * 200 + (tid >> 1);
    const int sub = tid & 1;           // which 8-state half of the channel

    float A2[8], Wr[13];
    bool fast = true;
#pragma unroll
    for (int n = 0; n < 8; ++n) {
        A2[n] = -__expf(A_log[d * 16 + sub * 8 + n]);
        fast = fast && (fabsf(A2[n] + (float)(sub * 8 + n + 1)) < 1e-3f);
    }
#pragma unroll
    for (int r = 0; r < 13; ++r) Wr[r] = dt_w[d * 13 + r];
    const float bdt = dt_b[d];
    const float Dv = Dw[d];

    const float* __restrict__ rp = xdbl + (size_t)b * LSEQ * 45;   // block-uniform
    bf16* __restrict__ xp = xz + (size_t)b * LSEQ * 800 + d;

    if (fast) scan_body<true>(rp, xp, Wr, A2, bdt, Dv, sub);
    else      scan_body<false>(rp, xp, Wr, A2, bdt, Dv, sub);
}

// ---------------- residual + layernorm over 200 ----------------
// Normal mode (outp == nullptr): writes f32 to dst and bf16 copy to dstb (dedicated buffer;
// dst==xb same-row in-place is safe: full row read into regs before any store).
// Final mode (outp != nullptr): writes ONLY the scattered output (c-slot for l==LSEQ-1,
// x_n slot otherwise) -- fuses the old write_out pass.
__global__ __launch_bounds__(256) void ln_res_kernel(const float* __restrict__ xa,
                                                     const float* xb,
                                                     const float* __restrict__ w,
                                                     const float* __restrict__ bias,
                                                     float* dst,
                                                     bf16* __restrict__ dstb, int rows,
                                                     float* __restrict__ outp, int b0) {
    int wave = threadIdx.x >> 6;
    int lane = threadIdx.x & 63;
    int row = blockIdx.x * 4 + wave;
    if (row >= rows) return;
    const float* pa = xa + (size_t)row * DM;
    const float* pb = xb + (size_t)row * DM;
    float v[4];
    float sum = 0.f, sq = 0.f;
#pragma unroll
    for (int i = 0; i < 4; ++i) {
        int c = lane + i * 64;
        float t = 0.f;
        if (c < DM) t = pa[c] + pb[c];
        v[i] = t;
        sum += t;
        sq += t * t;
    }
#pragma unroll
    for (int off = 32; off > 0; off >>= 1) {
        sum += __shfl_down(sum, off);
        sq += __shfl_down(sq, off);
    }
    sum = __shfl(sum, 0);
    sq = __shfl(sq, 0);
    float mu = sum * (1.f / DM);
    float var = fmaxf(sq * (1.f / DM) - mu * mu, 0.f);
    float rstd = rsqrtf(var + 1e-12f);
    if (outp) {
        int bb = b0 + row / LSEQ;
        int l = row % LSEQ;
        float* po = (l == LSEQ - 1)
                        ? outp + (size_t)bb * DM
                        : outp + (size_t)NB * DM + (size_t)(bb * (LSEQ - 1) + l) * DM;
#pragma unroll
        for (int i = 0; i < 4; ++i) {
            int c = lane + i * 64;
            if (c < DM) po[c] = (v[i] - mu) * rstd * w[c] + bias[c];
        }
    } else {
        float* pd = dst + (size_t)row * DM;
        bf16* pdb = dstb + (size_t)row * DM;
#pragma unroll
        for (int i = 0; i < 4; ++i) {
            int c = lane + i * 64;
            if (c < DM) {
                float o = (v[i] - mu) * rstd * w[c] + bias[c];
                pd[c] = o;
                pdb[c] = f2b(o);
            }
        }
    }
}

extern "C" void kernel_launch(void* const* d_in, const int* in_sizes, int n_in,
                              void* d_out, int out_size, void* d_ws, size_t ws_size,
                              hipStream_t stream) {
    fp emb       = (fp)d_in[0];
    fp in_proj_w = (fp)d_in[2];
    fp conv_w    = (fp)d_in[3];
    fp conv_b    = (fp)d_in[4];
    fp x_proj_w  = (fp)d_in[5];
    fp dt_proj_w = (fp)d_in[6];
    fp dt_proj_b = (fp)d_in[7];
    fp A_log     = (fp)d_in[8];
    fp Dw        = (fp)d_in[9];
    fp out_proj_w= (fp)d_in[10];
    fp ln1_w     = (fp)d_in[11];
    fp ln1_b     = (fp)d_in[12];
    fp ffn_w1    = (fp)d_in[13];
    fp ffn_b1    = (fp)d_in[14];
    fp ffn_w2    = (fp)d_in[15];
    fp ffn_b2    = (fp)d_in[16];
    fp ffn_ln_w  = (fp)d_in[17];
    fp ffn_ln_b  = (fp)d_in[18];

    // workspace per-row bytes: xz 1600 + hb 400 + xdbl 180 + m 800 + h 800 = 3780
    const int cands[8] = {256, 128, 64, 32, 16, 8, 4, 2};
    int cb = 2;
    for (int ci = 0; ci < 8; ++ci) {
        size_t rcx = (size_t)cands[ci] * LSEQ;
        if (rcx * 3780 + W_BYTES + 1024 <= ws_size) { cb = cands[ci]; break; }
    }
    const size_t rc = (size_t)cb * LSEQ;

    bf16*  wb   = (bf16*)d_ws;                     // packed bf16 weights
    bf16*  xz   = (bf16*)((char*)d_ws + W_BYTES);  // rc*800 bf16
    bf16*  hb   = xz + rc * 800;                   // rc*200 bf16 (GEMM-A activation copy)
    float* xdbl = (float*)(hb + rc * 200);         // rc*45 f32
    float* m    = xdbl + rc * 45;                  // rc*200 f32
    float* h    = m + rc * 200;                    // rc*200 f32

    // pre-convert all GEMM weights to bf16 (once per launch)
    wcvt_kernel<<<(W_TOTAL / 4 + 255) / 256, 256, 0, stream>>>(
        in_proj_w, x_proj_w, out_proj_w, ffn_w1, ffn_w2, wb);

    const int rcDM = (int)rc * DM;
    const int gm = (int)rc / 128;              // m-tiles

    for (int b0 = 0; b0 < NB; b0 += cb) {
        const float* emb_chunk = emb + (size_t)b0 * LSEQ * DM;

        // emb chunk -> bf16 into hb
        cvt_kernel<<<(rcDM / 4 + 255) / 256, 256, 0, stream>>>(emb_chunk, hb, rcDM / 4);

        for (int i = 0; i < 2; ++i) {
            const bf16* wb_in = wb + (size_t)i * 160000;
            const bf16* wb_xp = wb + W_XP_OFF + (size_t)i * 18000;
            const bf16* wb_op = wb + W_OP_OFF + (size_t)i * 80000;
            const bf16* wb_f1 = wb + W_F1_OFF + (size_t)i * 160000;
            const bf16* wb_f2 = wb + W_F2_OFF + (size_t)i * 160000;
            fp cw    = conv_w + (size_t)i * 400 * 4;
            fp cbp   = conv_b + (size_t)i * 400;
            fp w_dt  = dt_proj_w + (size_t)i * 400 * 13;
            fp b_dt  = dt_proj_b + (size_t)i * 400;
            fp Ai    = A_log + (size_t)i * 400 * 16;
            fp Di    = Dw + (size_t)i * 400;
            fp l1w   = ln1_w + (size_t)i * 200;
            fp l1b   = ln1_b + (size_t)i * 200;
            fp f1b   = ffn_b1 + (size_t)i * 800;
            fp f2b_  = ffn_b2 + (size_t)i * 200;
            fp flw   = ffn_ln_w + (size_t)i * 200;
            fp flb   = ffn_ln_b + (size_t)i * 200;

            const float* hin = (i == 0) ? emb_chunk : h;   // f32 residual source
            const bool last = (i == 1);

            // xz = hin @ in_proj^T (N=800, K=200); EPI5: z-half gets silu fused
            gemm_mfma<bf16, 5><<<dim3(gm, 7), 256, 0, stream>>>(
                hb, 200, wb_in, nullptr, xz, 800, 800, 200);
            // conv + silu in-place on x-half
            conv_silu_inplace<<<(cb * DIE + 255) / 256, 256, 0, stream>>>(xz, cw, cbp, cb * DIE);
            // xdbl = xc @ x_proj^T (N=45, K=400)
            gemm_mfma<float, 0><<<dim3(gm, 1), 256, 0, stream>>>(
                xz, 800, wb_xp, nullptr, xdbl, 45, 45, 400);
            // fused scan; y in-place on x-half (512 threads: 200 channels x 2 sub-lanes)
            scan_kernel<<<cb * 2, 512, 0, stream>>>(xdbl, xz, w_dt, b_dt, Ai, Di);
            // m = y @ out_proj^T (N=200, K=400)
            gemm_mfma<float, 0><<<dim3(gm, 2), 256, 0, stream>>>(
                xz, 800, wb_op, nullptr, m, 200, 200, 400);
            // h = ln(m + hin), f32 into h + bf16 into hb
            ln_res_kernel<<<rc / 4, 256, 0, stream>>>(m, hin, l1w, l1b, h, hb, (int)rc,
                                                      nullptr, 0);
            // f1 = gelu(h @ w1^T + b1) -> xz  (A = bf16 h in hb)
            gemm_mfma<bf16, 2><<<dim3(gm, 7), 256, 0, stream>>>(
                hb, 200, wb_f1, f1b, xz, 800, 800, 200);
            // f2 = f1 @ w2^T + b2 -> m (N=200, K=800)
            gemm_mfma<float, 3><<<dim3(gm, 2), 256, 0, stream>>>(
                xz, 800, wb_f2, f2b_, m, 200, 200, 800);
            // h = ln(f2 + h); final layer writes the scattered output directly
            ln_res_kernel<<<rc / 4, 256, 0, stream>>>(m, h, flw, flb, h, hb, (int)rc,
                                                      last ? (float*)d_out : nullptr, b0);
        }
    }
}